// Round 1
// baseline (534.011 us; speedup 1.0000x reference)
//
#include <hip/hip_runtime.h>
#include <hip/hip_bf16.h>

typedef short short8 __attribute__((ext_vector_type(8)));
typedef float f32x4 __attribute__((ext_vector_type(4)));
typedef unsigned short u16;

#define HD 16
#define DMODEL 1024
#define DKH 64
#define SEQ 2048

__device__ inline u16 f2bf(float f) {
  unsigned int x = __builtin_bit_cast(unsigned int, f);
  unsigned int r = (x + 0x7fffu + ((x >> 16) & 1u)) >> 16;
  return (u16)r;
}

// ---------------- weight transpose + fp32->bf16 ----------------
// W[k][n] fp32 -> WT[n][k] bf16, for 4 matrices (blockIdx.z)
__global__ __launch_bounds__(256) void wt_kernel(const float* __restrict__ W0,
                                                 const float* __restrict__ W1,
                                                 const float* __restrict__ W2,
                                                 const float* __restrict__ W3,
                                                 u16* __restrict__ T) {
  __shared__ float tile[64][65];
  const float* W = blockIdx.z == 0 ? W0 : blockIdx.z == 1 ? W1 : blockIdx.z == 2 ? W2 : W3;
  u16* out = T + (size_t)blockIdx.z * DMODEL * DMODEL;
  int n0 = blockIdx.x * 64, k0 = blockIdx.y * 64;
  int tx = threadIdx.x & 63, ty = threadIdx.x >> 6;
  for (int i = 0; i < 16; i++) {
    int r = ty + i * 4;
    tile[r][tx] = W[(size_t)(k0 + r) * DMODEL + n0 + tx];
  }
  __syncthreads();
  for (int i = 0; i < 16; i++) {
    int r = ty + i * 4;
    out[(size_t)(n0 + r) * DMODEL + k0 + tx] = f2bf(tile[tx][r]);
  }
}

// ---------------- GEMM: C[8192][1024] = A[8192][1024] * WT^T + bias ----------------
// AMODE: 0 = A fp32 (convert to bf16 while staging), 1 = A bf16
// OMODE: 0 = bf16 out, layout [B][H][S][DK]
//        1 = bf16 out, layout [B][H][DK][S]  (transposed V)
//        2 = fp32 out, layout [8192][1024]
template <int AMODE, int OMODE>
__global__ __launch_bounds__(256) void gemm_bt(const void* __restrict__ Av,
                                               const u16* __restrict__ Bt,
                                               const float* __restrict__ bias,
                                               void* __restrict__ Cv) {
  __shared__ u16 As[128 * 32];
  __shared__ u16 Bs[128 * 32];
  const int tid = threadIdx.x;
  const int lane = tid & 63, wid = tid >> 6;
  const int g = lane >> 4, c = lane & 15;
  const int m0 = blockIdx.y * 128, n0 = blockIdx.x * 128;
  const int wr = (wid >> 1) * 64, wc = (wid & 1) * 64;
  f32x4 acc[4][4] = {};

  for (int kt = 0; kt < 32; ++kt) {
    const int k0 = kt * 32;
    // ---- stage A tile 128x32 into LDS (bf16) ----
    if (AMODE == 0) {
      const float* A = (const float*)Av;
      int c4 = tid & 7, r = tid >> 3;  // 8 float4 per row, 32 rows per pass
      for (int p = 0; p < 4; ++p) {
        int row = r + p * 32;
        const float4 a = *(const float4*)(A + (size_t)(m0 + row) * DMODEL + k0 + c4 * 4);
        ushort4 u;
        u.x = f2bf(a.x); u.y = f2bf(a.y); u.z = f2bf(a.z); u.w = f2bf(a.w);
        *(ushort4*)(&As[row * 32 + c4 * 4]) = u;
      }
    } else {
      const u16* A = (const u16*)Av;
      int c8 = tid & 3, r = tid >> 2;  // 4 x (8 bf16) per row, 64 rows per pass
      for (int p = 0; p < 2; ++p) {
        int row = r + p * 64;
        *(uint4*)(&As[row * 32 + c8 * 8]) =
            *(const uint4*)(A + (size_t)(m0 + row) * DMODEL + k0 + c8 * 8);
      }
    }
    // ---- stage B tile 128x32 (WT rows = N) ----
    {
      int c8 = tid & 3, r = tid >> 2;
      for (int p = 0; p < 2; ++p) {
        int row = r + p * 64;
        *(uint4*)(&Bs[row * 32 + c8 * 8]) =
            *(const uint4*)(Bt + (size_t)(n0 + row) * DMODEL + k0 + c8 * 8);
      }
    }
    __syncthreads();
    short8 af[4], bfr[4];
    for (int mi = 0; mi < 4; ++mi)
      af[mi] = *(const short8*)(&As[(wr + mi * 16 + c) * 32 + g * 8]);
    for (int ni = 0; ni < 4; ++ni)
      bfr[ni] = *(const short8*)(&Bs[(wc + ni * 16 + c) * 32 + g * 8]);
    for (int mi = 0; mi < 4; ++mi)
      for (int ni = 0; ni < 4; ++ni)
        acc[mi][ni] = __builtin_amdgcn_mfma_f32_16x16x32_bf16(af[mi], bfr[ni], acc[mi][ni], 0, 0, 0);
    __syncthreads();
  }

  // ---- epilogue ----
  for (int ni = 0; ni < 4; ++ni) {
    const int colg = n0 + wc + ni * 16 + c;
    const float bv = bias[colg];
    for (int mi = 0; mi < 4; ++mi) {
      const int rowb = m0 + wr + mi * 16 + g * 4;  // j = 0..3 consecutive rows
      if (OMODE == 2) {
        float* C = (float*)Cv;
        for (int j = 0; j < 4; ++j)
          C[(size_t)(rowb + j) * DMODEL + colg] = acc[mi][ni][j] + bv;
      } else {
        const int b = rowb >> 11, s = rowb & 2047;
        const int h = colg >> 6, dk = colg & 63;
        u16* C = (u16*)Cv;
        if (OMODE == 0) {
          const size_t base = ((size_t)(b * HD + h)) * SEQ;
          for (int j = 0; j < 4; ++j)
            C[(base + s + j) * DKH + dk] = f2bf(acc[mi][ni][j] + bv);
        } else {
          const size_t base = ((size_t)(b * HD + h) * DKH + dk) * SEQ + s;
          ushort4 u;
          u.x = f2bf(acc[mi][ni][0] + bv);
          u.y = f2bf(acc[mi][ni][1] + bv);
          u.z = f2bf(acc[mi][ni][2] + bv);
          u.w = f2bf(acc[mi][ni][3] + bv);
          *(ushort4*)(&C[base]) = u;
        }
      }
    }
  }
}

// ---------------- flash attention ----------------
// Q,K: [B*H][S][DK] bf16 ; Vt: [B*H][DK][S] bf16 ; X out: [B][S][H*DK] bf16
__global__ __launch_bounds__(256) void attn_kernel(const u16* __restrict__ Q,
                                                   const u16* __restrict__ K,
                                                   const u16* __restrict__ Vt,
                                                   u16* __restrict__ X) {
  __shared__ u16 sP[4][32 * 72];  // per-wave P buffer, padded rows (16B-aligned)
  const int tid = threadIdx.x;
  const int lane = tid & 63, wid = tid >> 6;
  const int g = lane >> 4, c = lane & 15;
  const int bh = blockIdx.y;
  const int q0 = blockIdx.x * 128 + wid * 32;
  const u16* qb = Q + (size_t)bh * SEQ * DKH;
  const u16* kb = K + (size_t)bh * SEQ * DKH;
  const u16* vb = Vt + (size_t)bh * DKH * SEQ;

  // Q fragments held in registers for the whole kernel
  short8 qf[2][2];
  for (int mi = 0; mi < 2; ++mi)
    for (int kk = 0; kk < 2; ++kk)
      qf[mi][kk] = *(const short8*)(qb + (size_t)(q0 + mi * 16 + c) * DKH + kk * 32 + g * 8);

  f32x4 oacc[2][4] = {};
  float mrun[2][4], lrun[2][4];
  for (int mi = 0; mi < 2; ++mi)
    for (int j = 0; j < 4; ++j) { mrun[mi][j] = -1e30f; lrun[mi][j] = 0.f; }

  u16* myP = &sP[wid][0];

  for (int t = 0; t < SEQ / 64; ++t) {
    const int kv0 = t * 64;
    f32x4 sacc[2][4] = {};
    // S = Q K^T  (K fragments straight from global; L1/L2 reuse across waves/blocks)
    for (int kk = 0; kk < 2; ++kk) {
      short8 kf[4];
      for (int ni = 0; ni < 4; ++ni)
        kf[ni] = *(const short8*)(kb + (size_t)(kv0 + ni * 16 + c) * DKH + kk * 32 + g * 8);
      for (int mi = 0; mi < 2; ++mi)
        for (int ni = 0; ni < 4; ++ni)
          sacc[mi][ni] = __builtin_amdgcn_mfma_f32_16x16x32_bf16(qf[mi][kk], kf[ni], sacc[mi][ni], 0, 0, 0);
    }
    // online softmax (rows live in j x 16-lane groups)
    for (int mi = 0; mi < 2; ++mi) {
      float pm[4];
      for (int j = 0; j < 4; ++j) {
        float v = fmaxf(fmaxf(sacc[mi][0][j], sacc[mi][1][j]),
                        fmaxf(sacc[mi][2][j], sacc[mi][3][j]));
        pm[j] = v;
      }
      for (int d = 1; d < 16; d <<= 1)
        for (int j = 0; j < 4; ++j)
          pm[j] = fmaxf(pm[j], __shfl_xor(pm[j], d, 64));
      float rs[4];
      for (int j = 0; j < 4; ++j) {
        float mnew = fmaxf(mrun[mi][j], pm[j] * 0.125f);
        float alpha = __expf(mrun[mi][j] - mnew);
        mrun[mi][j] = mnew;
        lrun[mi][j] *= alpha;
        for (int ni = 0; ni < 4; ++ni) oacc[mi][ni][j] *= alpha;
        rs[j] = 0.f;
      }
      for (int ni = 0; ni < 4; ++ni)
        for (int j = 0; j < 4; ++j) {
          float p = __expf(sacc[mi][ni][j] * 0.125f - mrun[mi][j]);
          sacc[mi][ni][j] = p;
          rs[j] += p;
        }
      for (int d = 1; d < 16; d <<= 1)
        for (int j = 0; j < 4; ++j)
          rs[j] += __shfl_xor(rs[j], d, 64);
      for (int j = 0; j < 4; ++j) lrun[mi][j] += rs[j];
      // P -> LDS (bf16), transposing acc layout into row-major [q][kv]
      for (int ni = 0; ni < 4; ++ni)
        for (int j = 0; j < 4; ++j)
          myP[(mi * 16 + g * 4 + j) * 72 + ni * 16 + c] = f2bf(sacc[mi][ni][j]);
    }
    __syncthreads();
    // O += P V   (V fragments straight from global Vt[dk][s])
    for (int kk = 0; kk < 2; ++kk) {
      short8 pa[2], vf[4];
      for (int mi = 0; mi < 2; ++mi)
        pa[mi] = *(const short8*)(&myP[(mi * 16 + c) * 72 + kk * 32 + g * 8]);
      for (int ni = 0; ni < 4; ++ni)
        vf[ni] = *(const short8*)(vb + (size_t)(ni * 16 + c) * SEQ + kv0 + kk * 32 + g * 8);
      for (int mi = 0; mi < 2; ++mi)
        for (int ni = 0; ni < 4; ++ni)
          oacc[mi][ni] = __builtin_amdgcn_mfma_f32_16x16x32_bf16(pa[mi], vf[ni], oacc[mi][ni], 0, 0, 0);
    }
    __syncthreads();
  }

  // epilogue: X[b][s][h*64+dk] = O / l
  const int b = bh >> 4, h = bh & 15;
  for (int mi = 0; mi < 2; ++mi)
    for (int ni = 0; ni < 4; ++ni)
      for (int j = 0; j < 4; ++j) {
        int s = q0 + mi * 16 + g * 4 + j;
        float v = oacc[mi][ni][j] / lrun[mi][j];
        X[((size_t)(b * SEQ) + s) * DMODEL + h * DKH + ni * 16 + c] = f2bf(v);
      }
}

extern "C" void kernel_launch(void* const* d_in, const int* in_sizes, int n_in,
                              void* d_out, int out_size, void* d_ws, size_t ws_size,
                              hipStream_t stream) {
  (void)in_sizes; (void)n_in; (void)out_size; (void)ws_size;
  const float* query = (const float*)d_in[0];
  const float* key   = (const float*)d_in[1];
  const float* value = (const float*)d_in[2];
  const float* Wq = (const float*)d_in[3];
  const float* bq = (const float*)d_in[4];
  const float* Wk = (const float*)d_in[5];
  const float* bk = (const float*)d_in[6];
  const float* Wv = (const float*)d_in[7];
  const float* bv = (const float*)d_in[8];
  const float* Wo = (const float*)d_in[9];
  const float* bo = (const float*)d_in[10];
  float* out = (float*)d_out;

  char* ws = (char*)d_ws;
  const size_t MB = 1024 * 1024;
  u16* WT  = (u16*)ws;                 // 4 x 2MB: WqT, WkT, WvT, WoT
  u16* Qb  = (u16*)(ws + 8 * MB);      // 16 MB  [B*H][S][DK]
  u16* Kb  = (u16*)(ws + 24 * MB);     // 16 MB  [B*H][S][DK]
  u16* Vtb = (u16*)(ws + 40 * MB);     // 16 MB  [B*H][DK][S]
  u16* Xb  = (u16*)(ws + 56 * MB);     // 16 MB  [8192][1024]

  wt_kernel<<<dim3(16, 16, 4), 256, 0, stream>>>(Wq, Wk, Wv, Wo, WT);
  gemm_bt<0, 0><<<dim3(8, 64), 256, 0, stream>>>(query, WT,                bq, Qb);
  gemm_bt<0, 0><<<dim3(8, 64), 256, 0, stream>>>(key,   WT + 1 * 1048576,  bk, Kb);
  gemm_bt<0, 1><<<dim3(8, 64), 256, 0, stream>>>(value, WT + 2 * 1048576,  bv, Vtb);
  attn_kernel<<<dim3(16, 64), 256, 0, stream>>>(Qb, Kb, Vtb, Xb);
  gemm_bt<1, 2><<<dim3(8, 64), 256, 0, stream>>>(Xb, WT + 3 * 1048576,     bo, out);
}

// Round 2
// 391.779 us; speedup vs baseline: 1.3630x; 1.3630x over previous
//
#include <hip/hip_runtime.h>
#include <hip/hip_bf16.h>

typedef short short8 __attribute__((ext_vector_type(8)));
typedef float f32x4 __attribute__((ext_vector_type(4)));
typedef unsigned short u16;

#define HD 16
#define DMODEL 1024
#define DKH 64
#define SEQ 2048

typedef const __attribute__((address_space(1))) void gvoid;
typedef __attribute__((address_space(3))) void lvoid;

__device__ inline u16 f2bf(float f) {
  unsigned int x = __builtin_bit_cast(unsigned int, f);
  unsigned int r = (x + 0x7fffu + ((x >> 16) & 1u)) >> 16;
  return (u16)r;
}

// ---------------- weight transpose + fp32->bf16 ----------------
__global__ __launch_bounds__(256) void wt_kernel(const float* __restrict__ W0,
                                                 const float* __restrict__ W1,
                                                 const float* __restrict__ W2,
                                                 const float* __restrict__ W3,
                                                 u16* __restrict__ T) {
  __shared__ float tile[64][65];
  const float* W = blockIdx.z == 0 ? W0 : blockIdx.z == 1 ? W1 : blockIdx.z == 2 ? W2 : W3;
  u16* out = T + (size_t)blockIdx.z * DMODEL * DMODEL;
  int n0 = blockIdx.x * 64, k0 = blockIdx.y * 64;
  int tx = threadIdx.x & 63, ty = threadIdx.x >> 6;
  for (int i = 0; i < 16; i++) {
    int r = ty + i * 4;
    tile[r][tx] = W[(size_t)(k0 + r) * DMODEL + n0 + tx];
  }
  __syncthreads();
  for (int i = 0; i < 16; i++) {
    int r = ty + i * 4;
    out[(size_t)(n0 + r) * DMODEL + k0 + tx] = f2bf(tile[tx][r]);
  }
}

// ---------------- GEMM: C[8192][1024] = A[8192][1024] * WT^T + bias ----------------
template <int AMODE, int OMODE>
__global__ __launch_bounds__(256) void gemm_bt(const void* __restrict__ Av,
                                               const u16* __restrict__ Bt,
                                               const float* __restrict__ bias,
                                               void* __restrict__ Cv) {
  __shared__ u16 As[128 * 32];
  __shared__ u16 Bs[128 * 32];
  const int tid = threadIdx.x;
  const int lane = tid & 63, wid = tid >> 6;
  const int g = lane >> 4, c = lane & 15;
  const int m0 = blockIdx.y * 128, n0 = blockIdx.x * 128;
  const int wr = (wid >> 1) * 64, wc = (wid & 1) * 64;
  f32x4 acc[4][4] = {};

  for (int kt = 0; kt < 32; ++kt) {
    const int k0 = kt * 32;
    // ---- stage A tile 128x32 into LDS (bf16) ----
    if (AMODE == 0) {
      const float* A = (const float*)Av;
      int c4 = tid & 7, r = tid >> 3;
      for (int p = 0; p < 4; ++p) {
        int row = r + p * 32;
        const float4 a = *(const float4*)(A + (size_t)(m0 + row) * DMODEL + k0 + c4 * 4);
        ushort4 u;
        u.x = f2bf(a.x); u.y = f2bf(a.y); u.z = f2bf(a.z); u.w = f2bf(a.w);
        *(ushort4*)(&As[row * 32 + c4 * 4]) = u;
      }
    } else {
      const u16* A = (const u16*)Av;
      int c8 = tid & 3, r = tid >> 2;
      for (int p = 0; p < 2; ++p) {
        int row = r + p * 64;
        __builtin_amdgcn_global_load_lds(
            (gvoid*)(A + (size_t)(m0 + row) * DMODEL + k0 + c8 * 8),
            (lvoid*)(&As[row * 32 + c8 * 8]), 16, 0, 0);
      }
    }
    // ---- stage B tile 128x32 via global_load_lds ----
    {
      int c8 = tid & 3, r = tid >> 2;
      for (int p = 0; p < 2; ++p) {
        int row = r + p * 64;
        __builtin_amdgcn_global_load_lds(
            (gvoid*)(Bt + (size_t)(n0 + row) * DMODEL + k0 + c8 * 8),
            (lvoid*)(&Bs[row * 32 + c8 * 8]), 16, 0, 0);
      }
    }
    __syncthreads();
    short8 af[4], bfr[4];
    for (int mi = 0; mi < 4; ++mi)
      af[mi] = *(const short8*)(&As[(wr + mi * 16 + c) * 32 + g * 8]);
    for (int ni = 0; ni < 4; ++ni)
      bfr[ni] = *(const short8*)(&Bs[(wc + ni * 16 + c) * 32 + g * 8]);
    for (int mi = 0; mi < 4; ++mi)
      for (int ni = 0; ni < 4; ++ni)
        acc[mi][ni] = __builtin_amdgcn_mfma_f32_16x16x32_bf16(af[mi], bfr[ni], acc[mi][ni], 0, 0, 0);
    __syncthreads();
  }

  // ---- epilogue ----
  for (int ni = 0; ni < 4; ++ni) {
    const int colg = n0 + wc + ni * 16 + c;
    const float bv = bias[colg];
    for (int mi = 0; mi < 4; ++mi) {
      const int rowb = m0 + wr + mi * 16 + g * 4;
      if (OMODE == 2) {
        float* C = (float*)Cv;
        for (int j = 0; j < 4; ++j)
          C[(size_t)(rowb + j) * DMODEL + colg] = acc[mi][ni][j] + bv;
      } else {
        const int b = rowb >> 11, s = rowb & 2047;
        const int h = colg >> 6, dk = colg & 63;
        u16* C = (u16*)Cv;
        if (OMODE == 0) {
          const size_t base = ((size_t)(b * HD + h)) * SEQ;
          for (int j = 0; j < 4; ++j)
            C[(base + s + j) * DKH + dk] = f2bf(acc[mi][ni][j] + bv);
        } else {
          const size_t base = ((size_t)(b * HD + h) * DKH + dk) * SEQ + s;
          ushort4 u;
          u.x = f2bf(acc[mi][ni][0] + bv);
          u.y = f2bf(acc[mi][ni][1] + bv);
          u.z = f2bf(acc[mi][ni][2] + bv);
          u.w = f2bf(acc[mi][ni][3] + bv);
          *(ushort4*)(&C[base]) = u;
        }
      }
    }
  }
}

// ---------------- flash attention (swapped QK^T, barrier-free) ----------------
// Q,K: [B*H][S][DK] bf16 ; Vt: [B*H][DK][S] bf16 ; X out: [8192][1024] bf16
__global__ __launch_bounds__(256, 4) void attn_kernel(const u16* __restrict__ Q,
                                                      const u16* __restrict__ K,
                                                      const u16* __restrict__ Vt,
                                                      u16* __restrict__ X) {
  __shared__ u16 sP[4][32 * 72];  // wave-private P buffers
  const int tid = threadIdx.x;
  const int lane = tid & 63, wid = tid >> 6;
  const int g = lane >> 4, c = lane & 15;

  // bijective XCD swizzle: cluster all 16 q-tiles of a head on one XCD
  const int w = blockIdx.x + gridDim.x * blockIdx.y;  // 0..1023
  const int work = (w & 7) * 128 + (w >> 3);
  const int qt = work & 15, bh = work >> 4;

  const int q0 = qt * 128 + wid * 32;
  const u16* qb = Q + (size_t)bh * SEQ * DKH;
  const u16* kb = K + (size_t)bh * SEQ * DKH;
  const u16* vb = Vt + (size_t)bh * DKH * SEQ;

  // Q fragments (also valid as MFMA B-operand: lane -> col c, k = g*8..)
  short8 qf[2][2];
  for (int mi = 0; mi < 2; ++mi)
    for (int kk = 0; kk < 2; ++kk)
      qf[mi][kk] = *(const short8*)(qb + (size_t)(q0 + mi * 16 + c) * DKH + kk * 32 + g * 8);

  f32x4 oacc[2][4] = {};
  float mrun[2] = {-1e30f, -1e30f};
  float lrun[2] = {0.f, 0.f};
  u16* myP = &sP[wid][0];

  for (int t = 0; t < SEQ / 64; ++t) {
    const int kv0 = t * 64;
    f32x4 sacc[2][4] = {};  // [mi(q)][ni(kv)] of S^T: lane owns q=mi*16+c, kv=ni*16+g*4+j
    for (int kk = 0; kk < 2; ++kk) {
      short8 kf[4];
      for (int ni = 0; ni < 4; ++ni)
        kf[ni] = *(const short8*)(kb + (size_t)(kv0 + ni * 16 + c) * DKH + kk * 32 + g * 8);
      for (int mi = 0; mi < 2; ++mi)
        for (int ni = 0; ni < 4; ++ni)
          sacc[mi][ni] = __builtin_amdgcn_mfma_f32_16x16x32_bf16(kf[ni], qf[mi][kk], sacc[mi][ni], 0, 0, 0);
    }

    // online softmax: each lane owns one q-row (16 kv vals) per mi
    for (int mi = 0; mi < 2; ++mi) {
      float pm = sacc[mi][0][0];
      for (int ni = 0; ni < 4; ++ni)
        for (int j = 0; j < 4; ++j) pm = fmaxf(pm, sacc[mi][ni][j]);
      pm = fmaxf(pm, __shfl_xor(pm, 16, 64));
      pm = fmaxf(pm, __shfl_xor(pm, 32, 64));

      const bool skip = __all(pm * 0.125f <= mrun[mi] + 8.0f);
      float a = 1.0f;
      if (!skip) {
        float mnew = fmaxf(mrun[mi], pm * 0.125f);
        a = __expf(mrun[mi] - mnew);
        mrun[mi] = mnew;
      }
      const float mcur = mrun[mi];
      float rs = 0.f;
      for (int ni = 0; ni < 4; ++ni)
        for (int j = 0; j < 4; ++j) {
          float p = __expf(sacc[mi][ni][j] * 0.125f - mcur);
          sacc[mi][ni][j] = p;
          rs += p;
        }
      rs += __shfl_xor(rs, 16, 64);
      rs += __shfl_xor(rs, 32, 64);
      lrun[mi] = lrun[mi] * a + rs;

      // pack P row-major [q][kv] (2-way-conflict-free)
      for (int ni = 0; ni < 4; ++ni) {
        ushort4 u;
        u.x = f2bf(sacc[mi][ni][0]);
        u.y = f2bf(sacc[mi][ni][1]);
        u.z = f2bf(sacc[mi][ni][2]);
        u.w = f2bf(sacc[mi][ni][3]);
        *(ushort4*)(&myP[(mi * 16 + c) * 72 + ni * 16 + g * 4]) = u;
      }

      if (!skip) {  // redistribute alpha to oacc row layout (q = g*4+j)
        float a0 = __shfl(a, 20 * g + 0, 64);
        float a1 = __shfl(a, 20 * g + 1, 64);
        float a2 = __shfl(a, 20 * g + 2, 64);
        float a3 = __shfl(a, 20 * g + 3, 64);
        for (int ni = 0; ni < 4; ++ni) {
          oacc[mi][ni][0] *= a0;
          oacc[mi][ni][1] *= a1;
          oacc[mi][ni][2] *= a2;
          oacc[mi][ni][3] *= a3;
        }
      }
    }

    // V fragments straight from global (B-operand: lane col dk=ni*16+c, k=kv contiguous)
    short8 vf[4][2];
    for (int ni = 0; ni < 4; ++ni)
      for (int kk = 0; kk < 2; ++kk)
        vf[ni][kk] = *(const short8*)(vb + (size_t)(ni * 16 + c) * SEQ + kv0 + kk * 32 + g * 8);

    // P back as A-fragments (row q=mi*16+c, k=kv)
    short8 pa[2][2];
    for (int mi = 0; mi < 2; ++mi)
      for (int kk = 0; kk < 2; ++kk)
        pa[mi][kk] = *(const short8*)(&myP[(mi * 16 + c) * 72 + kk * 32 + g * 8]);

    for (int kk = 0; kk < 2; ++kk)
      for (int mi = 0; mi < 2; ++mi)
        for (int ni = 0; ni < 4; ++ni)
          oacc[mi][ni] = __builtin_amdgcn_mfma_f32_16x16x32_bf16(pa[mi][kk], vf[ni][kk], oacc[mi][ni], 0, 0, 0);
  }

  // epilogue: X[b*S+s][h*64+dk] = O / l  (oacc rows q = mi*16+g*4+j)
  const int b = bh >> 4, h = bh & 15;
  for (int mi = 0; mi < 2; ++mi) {
    float l0 = __shfl(lrun[mi], 20 * g + 0, 64);
    float l1 = __shfl(lrun[mi], 20 * g + 1, 64);
    float l2 = __shfl(lrun[mi], 20 * g + 2, 64);
    float l3 = __shfl(lrun[mi], 20 * g + 3, 64);
    float inv[4] = {1.f / l0, 1.f / l1, 1.f / l2, 1.f / l3};
    for (int ni = 0; ni < 4; ++ni)
      for (int j = 0; j < 4; ++j) {
        int s = q0 + mi * 16 + g * 4 + j;
        X[((size_t)(b * SEQ) + s) * DMODEL + h * DKH + ni * 16 + c] =
            f2bf(oacc[mi][ni][j] * inv[j]);
      }
  }
}

extern "C" void kernel_launch(void* const* d_in, const int* in_sizes, int n_in,
                              void* d_out, int out_size, void* d_ws, size_t ws_size,
                              hipStream_t stream) {
  (void)in_sizes; (void)n_in; (void)out_size; (void)ws_size;
  const float* query = (const float*)d_in[0];
  const float* key   = (const float*)d_in[1];
  const float* value = (const float*)d_in[2];
  const float* Wq = (const float*)d_in[3];
  const float* bq = (const float*)d_in[4];
  const float* Wk = (const float*)d_in[5];
  const float* bk = (const float*)d_in[6];
  const float* Wv = (const float*)d_in[7];
  const float* bv = (const float*)d_in[8];
  const float* Wo = (const float*)d_in[9];
  const float* bo = (const float*)d_in[10];
  float* out = (float*)d_out;

  char* ws = (char*)d_ws;
  const size_t MB = 1024 * 1024;
  u16* WT  = (u16*)ws;                 // 4 x 2MB: WqT, WkT, WvT, WoT
  u16* Qb  = (u16*)(ws + 8 * MB);      // 16 MB  [B*H][S][DK]
  u16* Kb  = (u16*)(ws + 24 * MB);     // 16 MB  [B*H][S][DK]
  u16* Vtb = (u16*)(ws + 40 * MB);     // 16 MB  [B*H][DK][S]
  u16* Xb  = (u16*)(ws + 56 * MB);     // 16 MB  [8192][1024]

  wt_kernel<<<dim3(16, 16, 4), 256, 0, stream>>>(Wq, Wk, Wv, Wo, WT);
  gemm_bt<0, 0><<<dim3(8, 64), 256, 0, stream>>>(query, WT,                bq, Qb);
  gemm_bt<0, 0><<<dim3(8, 64), 256, 0, stream>>>(key,   WT + 1 * 1048576,  bk, Kb);
  gemm_bt<0, 1><<<dim3(8, 64), 256, 0, stream>>>(value, WT + 2 * 1048576,  bv, Vtb);
  attn_kernel<<<dim3(16, 64), 256, 0, stream>>>(Qb, Kb, Vtb, Xb);
  gemm_bt<1, 2><<<dim3(8, 64), 256, 0, stream>>>(Xb, WT + 3 * 1048576,     bo, out);
}